// Round 4
// baseline (249.902 us; speedup 1.0000x reference)
//
#include <hip/hip_runtime.h>
#include <hip/hip_bf16.h>

// B=16, C=256, H=W=64 (N=4096), HEADS=8, HD=32, GROUPS=4, EPS=1e-5
// Pipeline:
//  K1 gn_partial : partial sum/sumsq per (b,g,part)
//  K2 finalize   : mu/rstd + qkv_weight->bf16 + WqT (bf16 [c][d])
//  K3 norm_t     : xnT[b][n][c] = GN(x) bf16
//  K4 attfused   : per (b,h,ns): S=Wkv_h.xn^T in-reg, exp, att += P.V^T (atomics)
//  K5 makeM      : P[b][o][hd] = sum_e proj[o][he] attg[h,d,e]/rsum  (bf16)
//  K6 gemm_bt    : M2[b][o][c] = P . WqT^T   (= P.Wq)                (bf16)
//  K7 gemm_final : out[b][o][n] = M2 . xnT^T + bias  (M=256 x N=64 tiles)
// Folding: proj@out = (P@Wq)@xn = M2@xn ; kv never materialized to HBM.

typedef __attribute__((ext_vector_type(4))) float f32x4;
typedef __attribute__((ext_vector_type(8))) short bf16x8;
typedef __attribute__((ext_vector_type(4))) short s16x4;
typedef __attribute__((ext_vector_type(8))) unsigned short u16x8;

__device__ inline float b2f(unsigned short u) {
  unsigned int x = ((unsigned int)u) << 16;
  float f; __builtin_memcpy(&f, &x, 4); return f;
}
__device__ inline unsigned short f2b(float f) {
  unsigned int x; __builtin_memcpy(&x, &f, 4);
  x += 0x7FFFu + ((x >> 16) & 1u);            // RNE
  return (unsigned short)(x >> 16);
}

// ---------------- K1: GN partial sums ----------------
__global__ void __launch_bounds__(256) k_gn_partial(const float* __restrict__ x,
                                                    float* __restrict__ partials) {
  int blk = blockIdx.x;           // 64 groups * 16 parts
  int grp = blk >> 4;
  int part = blk & 15;
  const float* base = x + (size_t)grp * 262144 + (size_t)part * 16384;
  int t = threadIdx.x;
  float s = 0.f, s2 = 0.f;
  for (int i = 0; i < 16; ++i) {
    f32x4 v = *(const f32x4*)(base + (size_t)(i * 256 + t) * 4);
    s  += v[0] + v[1] + v[2] + v[3];
    s2 += v[0]*v[0] + v[1]*v[1] + v[2]*v[2] + v[3]*v[3];
  }
  for (int o = 32; o > 0; o >>= 1) { s += __shfl_down(s, o); s2 += __shfl_down(s2, o); }
  __shared__ float ls[4], ls2[4];
  int w = t >> 6;
  if ((t & 63) == 0) { ls[w] = s; ls2[w] = s2; }
  __syncthreads();
  if (t == 0) {
    partials[blk * 2] = ls[0] + ls[1] + ls[2] + ls[3];
    partials[blk * 2 + 1] = ls2[0] + ls2[1] + ls2[2] + ls2[3];
  }
}

// ---------------- K2: finalize stats + qkv weight -> bf16 + WqT ----------------
__global__ void __launch_bounds__(256) k_finalize(const float* __restrict__ partials,
                                                  float* __restrict__ stats,
                                                  const float* __restrict__ qkvw,
                                                  unsigned short* __restrict__ Wb,
                                                  unsigned short* __restrict__ WqT) {
  int bx = blockIdx.x, t = threadIdx.x;
  if (bx == 0) {
    if (t < 64) {
      float S = 0.f, S2 = 0.f;
      for (int i = 0; i < 16; ++i) { S += partials[(t * 16 + i) * 2]; S2 += partials[(t * 16 + i) * 2 + 1]; }
      float mu = S * (1.f / 262144.f);
      float var = S2 * (1.f / 262144.f) - mu * mu;
      stats[t * 2] = mu;
      stats[t * 2 + 1] = rsqrtf(var + 1e-5f);
    }
  } else if (bx <= 192) {
    int idx = (bx - 1) * 256 + t;               // float4 index, 49152 total
    f32x4 v = *(const f32x4*)(qkvw + (size_t)idx * 4);
    s16x4 o;
    for (int i = 0; i < 4; ++i) o[i] = (short)f2b(v[i]);
    *(s16x4*)(Wb + (size_t)idx * 4) = o;
  } else {
    // WqT[c][d] = qkvw[d][c], bf16, 256x256.  16 blocks (193..208).
    int bb = bx - 193;
    int c = bb * 16 + (t & 15);
    int d0 = (t >> 4) * 16;
    for (int i = 0; i < 16; ++i) {
      int d = d0 + i;
      WqT[(size_t)c * 256 + d] = f2b(qkvw[(size_t)d * 256 + c]);
    }
  }
}

// ---------------- K3: GroupNorm apply + transpose -> xnT[b][n][c] bf16 ----------------
__global__ void __launch_bounds__(256) k_norm_t(const float* __restrict__ x,
                                                const float* __restrict__ stats,
                                                const float* __restrict__ gamma,
                                                const float* __restrict__ beta,
                                                unsigned short* __restrict__ xnT) {
  int blk = blockIdx.x;           // 16 b * 256 tiles
  int b = blk >> 8;
  int tile = blk & 255;
  int ct = tile >> 6;
  int nt = tile & 63;
  int c0 = ct * 64, n0 = nt * 64;
  __shared__ float T[64][65];
  int t = threadIdx.x;
  float mu = stats[(b * 4 + ct) * 2];
  float rs = stats[(b * 4 + ct) * 2 + 1];
  int cl = t >> 2, q4 = t & 3;
  float sc = gamma[c0 + cl] * rs;
  float off = beta[c0 + cl] - mu * sc;
  const float* xr = x + ((size_t)b * 256 + c0 + cl) * 4096 + n0;
  for (int p = 0; p < 4; ++p) {
    int col = p * 16 + q4 * 4;
    f32x4 v = *(const f32x4*)(xr + col);
    for (int i = 0; i < 4; ++i) T[cl][col + i] = v[i] * sc + off;
  }
  __syncthreads();
  int nl = t >> 2, cc = t & 3;
  u16x8 o0, o1;
  for (int i = 0; i < 8; ++i) o0[i] = f2b(T[cc * 16 + i][nl]);
  for (int i = 0; i < 8; ++i) o1[i] = f2b(T[cc * 16 + 8 + i][nl]);
  unsigned short* dst = xnT + ((size_t)b * 4096 + n0 + nl) * 256 + c0 + cc * 16;
  *(u16x8*)dst = o0;
  *(u16x8*)(dst + 8) = o1;
}

// ---------------- K4: fused kv-GEMM + exp + att accumulation ----------------
// grid: x = 64 ((b<<2)|ns), y = 8 (h). 8 head-blocks of one (b,ns) share an XCD
// (linear ids differ by 64 == 0 mod 8) -> xnT slice served from L2.
__global__ void __launch_bounds__(256) k_attfused(const unsigned short* __restrict__ Wb,
                                                  const unsigned short* __restrict__ xnT,
                                                  float* __restrict__ attg,
                                                  float* __restrict__ rsums) {
  const int bx = blockIdx.x;
  const int b = bx >> 2, ns = bx & 3, h = blockIdx.y;
  const int hb = b * 8 + h;
  const int t = threadIdx.x;
  const int wave = t >> 6, lane = t & 63;
  const int g = lane >> 4, r = lane & 15;
  const int rh = wave >> 1;             // 0 = k-rows (d), 1 = v-rows (e)
  const int ch = wave & 1;              // n-col half of the 64-chunk
  __shared__ unsigned short PL[2][32][72];   // [d][n-chunk64], 144B rows (16B-aligned)
  __shared__ unsigned short VL[2][32][72];   // [e][n-chunk64]

  // preload W A-frags: k rows at qkv 256+h*32, v rows at 512+h*32
  const unsigned short* Wrow = Wb + (size_t)(256 + rh * 256 + h * 32) * 256;
  bf16x8 af[2][8];
#pragma unroll
  for (int rt = 0; rt < 2; ++rt)
#pragma unroll
    for (int kt = 0; kt < 8; ++kt)
      af[rt][kt] = *(const bf16x8*)(Wrow + (size_t)(rt * 16 + r) * 256 + kt * 32 + 8 * g);

  const unsigned short* Xb = xnT + ((size_t)b * 4096 + ns * 1024 + ch * 32 + r) * 256 + 8 * g;
  f32x4 attacc = {0.f, 0.f, 0.f, 0.f};
  float rs[2][4] = {{0.f,0.f,0.f,0.f},{0.f,0.f,0.f,0.f}};

  for (int c = 0; c < 16; ++c) {
    const int cur = c & 1;
    // ---- B-frags direct global->reg for this 64-chunk (own col-half) ----
    const unsigned short* Xc = Xb + (size_t)(c * 64) * 256;
    bf16x8 bfr[8][2];
#pragma unroll
    for (int kt = 0; kt < 8; ++kt)
#pragma unroll
      for (int ct = 0; ct < 2; ++ct)
        bfr[kt][ct] = *(const bf16x8*)(Xc + (size_t)(ct * 16) * 256 + kt * 32);
    // ---- S(32x32 per wave) = W . xn^T over K=256 ----
    f32x4 sacc[2][2] = {};
#pragma unroll
    for (int kt = 0; kt < 8; ++kt)
#pragma unroll
      for (int rt = 0; rt < 2; ++rt)
#pragma unroll
        for (int ct = 0; ct < 2; ++ct)
          sacc[rt][ct] = __builtin_amdgcn_mfma_f32_16x16x32_bf16(
              af[rt][kt], bfr[kt][ct], sacc[rt][ct], 0, 0, 0);
    // ---- exp (k) / passthrough (v) -> PL/VL bf16, C-layout scatter ----
    if (rh == 0) {
#pragma unroll
      for (int rt = 0; rt < 2; ++rt)
#pragma unroll
        for (int ct = 0; ct < 2; ++ct)
#pragma unroll
          for (int reg = 0; reg < 4; ++reg) {
            float e = __expf(sacc[rt][ct][reg]);
            rs[rt][reg] += e;
            PL[cur][rt * 16 + 4 * g + reg][ch * 32 + ct * 16 + r] = f2b(e);
          }
    } else {
#pragma unroll
      for (int rt = 0; rt < 2; ++rt)
#pragma unroll
        for (int ct = 0; ct < 2; ++ct)
#pragma unroll
          for (int reg = 0; reg < 4; ++reg)
            VL[cur][rt * 16 + 4 * g + reg][ch * 32 + ct * 16 + r] = f2b(sacc[rt][ct][reg]);
    }
    __syncthreads();
    // ---- att quadrant (rh,ch) += P . V^T over 64 n ----
#pragma unroll
    for (int ks = 0; ks < 2; ++ks) {
      bf16x8 pa = *(const bf16x8*)&PL[cur][rh * 16 + r][ks * 32 + 8 * g];
      bf16x8 vb = *(const bf16x8*)&VL[cur][ch * 16 + r][ks * 32 + 8 * g];
      attacc = __builtin_amdgcn_mfma_f32_16x16x32_bf16(pa, vb, attacc, 0, 0, 0);
    }
  }
  // ---- global accumulate ----
  float* ab = attg + (size_t)hb * 1024;
#pragma unroll
  for (int reg = 0; reg < 4; ++reg)
    atomicAdd(&ab[(rh * 16 + 4 * g + reg) * 32 + ch * 16 + r], attacc[reg]);
  if (rh == 0) {
#pragma unroll
    for (int rt = 0; rt < 2; ++rt)
#pragma unroll
      for (int reg = 0; reg < 4; ++reg) {
        float v = rs[rt][reg];
        v += __shfl_xor(v, 1); v += __shfl_xor(v, 2);
        v += __shfl_xor(v, 4); v += __shfl_xor(v, 8);
        if (r == 0) atomicAdd(&rsums[hb * 32 + rt * 16 + 4 * g + reg], v);
      }
  }
}

// ---------------- gemm_bt: C[M][N] = A[M][256].B[N][256]^T (small M2 GEMM) ----------
template<bool OUT_BF16, bool ADD_BIAS>
__global__ void __launch_bounds__(256)
k_gemm_bt(const unsigned short* __restrict__ A,
          const unsigned short* __restrict__ B,
          void* __restrict__ Cv,
          const float* __restrict__ bias,
          long sA, long sB, long sC, int ldc) {
  __shared__ unsigned short LA[128][32];
  __shared__ unsigned short LB[128][32];
  const int t = threadIdx.x;
  const unsigned short* Ab = A + (size_t)blockIdx.z * sA + (size_t)blockIdx.x * 128 * 256;
  const unsigned short* Bb = B + (size_t)blockIdx.z * sB + (size_t)blockIdx.y * 128 * 256;
  const int wave = t >> 6, lane = t & 63;
  const int wm = wave >> 1, wn = wave & 1;
  const int g = lane >> 4, r = lane & 15;
  const int rA = t >> 2, sslot = t & 3;
  const int ws0 = 8 * (sslot ^ (rA & 3));
  const int rslot = 8 * (g ^ (r & 3));
  const unsigned short* ag = Ab + (size_t)rA * 256 + 8 * sslot;
  const unsigned short* bg = Bb + (size_t)rA * 256 + 8 * sslot;
  u16x8 pa0 = *(const u16x8*)(ag);
  u16x8 pa1 = *(const u16x8*)(ag + 64 * 256);
  u16x8 pb0 = *(const u16x8*)(bg);
  u16x8 pb1 = *(const u16x8*)(bg + 64 * 256);
  f32x4 acc[4][4] = {};
  for (int kt = 0; kt < 8; ++kt) {
    if (kt) __syncthreads();
    *(u16x8*)&LA[rA][ws0] = pa0;  *(u16x8*)&LA[rA + 64][ws0] = pa1;
    *(u16x8*)&LB[rA][ws0] = pb0;  *(u16x8*)&LB[rA + 64][ws0] = pb1;
    __syncthreads();
    if (kt < 7) {
      int off = (kt + 1) * 32;
      pa0 = *(const u16x8*)(ag + off);  pa1 = *(const u16x8*)(ag + 64 * 256 + off);
      pb0 = *(const u16x8*)(bg + off);  pb1 = *(const u16x8*)(bg + 64 * 256 + off);
    }
    bf16x8 af[4], bfr[4];
    for (int i = 0; i < 4; ++i) {
      af[i]  = *(const bf16x8*)&LA[wm * 64 + i * 16 + r][rslot];
      bfr[i] = *(const bf16x8*)&LB[wn * 64 + i * 16 + r][rslot];
    }
    for (int mi = 0; mi < 4; ++mi)
      for (int ni = 0; ni < 4; ++ni)
        acc[mi][ni] = __builtin_amdgcn_mfma_f32_16x16x32_bf16(af[mi], bfr[ni], acc[mi][ni], 0, 0, 0);
  }
  const int m0 = blockIdx.x * 128 + wm * 64;
  const int n0 = blockIdx.y * 128 + wn * 64;
  if (OUT_BF16) {
    unsigned short* C = (unsigned short*)Cv + (size_t)blockIdx.z * sC;
    for (int mi = 0; mi < 4; ++mi)
      for (int ni = 0; ni < 4; ++ni) {
        int row = m0 + mi * 16 + 4 * g;
        int col = n0 + ni * 16 + r;
        for (int reg = 0; reg < 4; ++reg)
          C[(size_t)(row + reg) * ldc + col] = f2b(acc[mi][ni][reg]);
      }
  } else {
    float* C = (float*)Cv + (size_t)blockIdx.z * sC;
    for (int mi = 0; mi < 4; ++mi)
      for (int ni = 0; ni < 4; ++ni) {
        int row = m0 + mi * 16 + 4 * g;
        int col = n0 + ni * 16 + r;
        for (int reg = 0; reg < 4; ++reg) {
          float v = acc[mi][ni][reg];
          if (ADD_BIAS) v += bias[row + reg];
          C[(size_t)(row + reg) * ldc + col] = v;
        }
      }
  }
}

// ---------------- K5: P[b][o][hd] = sum_e proj[o][he] * attg[h,d,e]/rsum[d] ----------------
__global__ void __launch_bounds__(256) k_makeM(const float* __restrict__ attg,
                                               const float* __restrict__ rsums,
                                               const float* __restrict__ projw,
                                               unsigned short* __restrict__ Mb) {
  int blk = blockIdx.x;           // 16*8 (b,h)
  int b = blk >> 3, h = blk & 7;
  __shared__ float attL[32][33];
  __shared__ float invs[32];
  int t = threadIdx.x;
  if (t < 32) invs[t] = 1.f / rsums[blk * 32 + t];
  const float* asrc = attg + (size_t)blk * 1024;
  {
    f32x4 v = *(const f32x4*)(asrc + (size_t)t * 4);
    int idx = t * 4;
    for (int i = 0; i < 4; ++i) attL[(idx + i) >> 5][(idx + i) & 31] = v[i];
  }
  __syncthreads();
  float pw[32];
  const float* ps = projw + (size_t)t * 256 + h * 32;
  for (int i = 0; i < 8; ++i) {
    f32x4 v = *(const f32x4*)(ps + i * 4);
    pw[i * 4 + 0] = v[0]; pw[i * 4 + 1] = v[1]; pw[i * 4 + 2] = v[2]; pw[i * 4 + 3] = v[3];
  }
  unsigned short* dst = Mb + ((size_t)b * 256 + t) * 256 + h * 32;
  for (int dd = 0; dd < 32; ++dd) {
    float s = 0.f;
    for (int e = 0; e < 32; ++e) s += pw[e] * attL[dd][e];
    dst[dd] = f2b(s * invs[dd]);
  }
}

// ---------------- K7: out[b][o][nt*64..] = M2[b] . xnT^T + bias  (M=256, N=64) ----------
__global__ void __launch_bounds__(256) k_gemm_final(const unsigned short* __restrict__ M2,
                                                    const unsigned short* __restrict__ xnT,
                                                    float* __restrict__ out,
                                                    const float* __restrict__ bias) {
  const int nt = blockIdx.x, b = blockIdx.y;
  const unsigned short* Ab = M2 + (size_t)b * 65536;
  const unsigned short* Bb = xnT + ((size_t)b * 4096 + nt * 64) * 256;
  float* Cb = out + (size_t)b * 1048576 + (size_t)nt * 64;
  __shared__ unsigned short LB[2][64][32];
  const int t = threadIdx.x;
  const int wave = t >> 6, lane = t & 63, g = lane >> 4, r = lane & 15;
  const int srow = t >> 2, sslot = t & 3;
  const int ws0 = 8 * (sslot ^ (srow & 3));
  const int rslot = 8 * (g ^ (r & 3));
  const unsigned short* bg = Bb + (size_t)srow * 256 + 8 * sslot;
  const unsigned short* ar = Ab + (size_t)(wave * 64 + r) * 256 + 8 * g;
  u16x8 pb = *(const u16x8*)bg;
  f32x4 acc[4][4] = {};
  for (int kt = 0; kt < 8; ++kt) {
    const int cur = kt & 1;
    *(u16x8*)&LB[cur][srow][ws0] = pb;
    __syncthreads();
    if (kt < 7) pb = *(const u16x8*)(bg + (kt + 1) * 32);
    bf16x8 af[4], bfr[4];
#pragma unroll
    for (int mi = 0; mi < 4; ++mi)
      af[mi] = *(const bf16x8*)(ar + (size_t)(mi * 16) * 256 + kt * 32);
#pragma unroll
    for (int ni = 0; ni < 4; ++ni)
      bfr[ni] = *(const bf16x8*)&LB[cur][ni * 16 + r][rslot];
#pragma unroll
    for (int mi = 0; mi < 4; ++mi)
#pragma unroll
      for (int ni = 0; ni < 4; ++ni)
        acc[mi][ni] = __builtin_amdgcn_mfma_f32_16x16x32_bf16(af[mi], bfr[ni], acc[mi][ni], 0, 0, 0);
  }
#pragma unroll
  for (int mi = 0; mi < 4; ++mi) {
    const int row = wave * 64 + mi * 16 + 4 * g;
#pragma unroll
    for (int ni = 0; ni < 4; ++ni)
#pragma unroll
      for (int reg = 0; reg < 4; ++reg)
        Cb[(size_t)(row + reg) * 4096 + ni * 16 + r] = acc[mi][ni][reg] + bias[row + reg];
  }
}

extern "C" void kernel_launch(void* const* d_in, const int* in_sizes, int n_in,
                              void* d_out, int out_size, void* d_ws, size_t ws_size,
                              hipStream_t stream) {
  (void)in_sizes; (void)n_in; (void)out_size; (void)ws_size;
  const float* x     = (const float*)d_in[0];
  const float* gn_w  = (const float*)d_in[1];
  const float* gn_b  = (const float*)d_in[2];
  const float* qkvw  = (const float*)d_in[3];
  const float* projw = (const float*)d_in[4];
  const float* projb = (const float*)d_in[5];

  char* ws = (char*)d_ws;
  float*          partials = (float*)(ws);                       //   8 KB
  float*          stats    = (float*)(ws + 8192);                //  512 B
  unsigned short* Wb       = (unsigned short*)(ws + 16384);      //  384 KB (768x256)
  unsigned short* Mb       = (unsigned short*)(ws + 409600);     //    2 MB (P: 16x256x256)
  float*          attg     = (float*)(ws + 2506752);             //  512 KB (16x8x32x32)
  float*          rsums    = (float*)(ws + 3031040);             //   16 KB (16x8x32)
  unsigned short* WqT      = (unsigned short*)(ws + 3047424);    //  128 KB (256x256)
  unsigned short* M2       = (unsigned short*)(ws + 3178496);    //    2 MB (16x256x256)
  unsigned short* xnT      = (unsigned short*)(ws + 8388608);    //   32 MB (16x4096x256)

  k_gn_partial<<<1024, 256, 0, stream>>>(x, partials);
  k_finalize<<<209, 256, 0, stream>>>(partials, stats, qkvw, Wb, WqT);
  k_norm_t<<<4096, 256, 0, stream>>>(x, stats, gn_w, gn_b, xnT);
  (void)hipMemsetAsync(attg, 0, 540672, stream);   // attg + rsums (contiguous)
  k_attfused<<<dim3(64, 8), 256, 0, stream>>>(Wb, xnT, attg, rsums);
  k_makeM<<<128, 256, 0, stream>>>(attg, rsums, projw, Mb);
  // M2[b][256][256] = P . WqT^T  (= P.Wq)
  k_gemm_bt<true, false><<<dim3(2, 2, 16), 256, 0, stream>>>(
      Mb, WqT, (void*)M2, nullptr, 65536L, 0L, 65536L, 256);
  // out[b][256][4096] = M2 . xnT^T + bias
  k_gemm_final<<<dim3(64, 16), 256, 0, stream>>>(M2, xnT, (float*)d_out, projb);
}

// Round 5
// 239.969 us; speedup vs baseline: 1.0414x; 1.0414x over previous
//
#include <hip/hip_runtime.h>
#include <hip/hip_bf16.h>

// B=16, C=256, H=W=64 (N=4096), HEADS=8, HD=32, GROUPS=4, EPS=1e-5
// Pipeline:
//  K1 gn_partial : partial sum/sumsq per (b,g,part)
//  K2 finalize   : mu/rstd + qkv_weight->bf16 + WqT (bf16 [c][d])
//  K3 norm_t     : xnT[b][n][c] = GN(x) bf16
//  K4 attfused   : per (b,h,ns): S=Wkv_h.xn^T in-reg, exp, att += P.V^T (atomics)
//  K5 makeM      : P[b][o][hd] = sum_e proj[o][he] attg[h,d,e]/rsum  (bf16)
//  K6 gemm_bt    : M2[b][o][c] = P . WqT^T   (= P.Wq)                (bf16)
//  K7 gemm_final : out[b][o][n] = M2 . xnT^T + bias  (M=256 x N=64 tiles)
// Folding: proj@out = (P@Wq)@xn = M2@xn ; kv never materialized to HBM.

typedef __attribute__((ext_vector_type(4))) float f32x4;
typedef __attribute__((ext_vector_type(8))) short bf16x8;
typedef __attribute__((ext_vector_type(4))) short s16x4;
typedef __attribute__((ext_vector_type(8))) unsigned short u16x8;

__device__ inline float b2f(unsigned short u) {
  unsigned int x = ((unsigned int)u) << 16;
  float f; __builtin_memcpy(&f, &x, 4); return f;
}
__device__ inline unsigned short f2b(float f) {
  unsigned int x; __builtin_memcpy(&x, &f, 4);
  x += 0x7FFFu + ((x >> 16) & 1u);            // RNE
  return (unsigned short)(x >> 16);
}

// ---------------- K1: GN partial sums ----------------
__global__ void __launch_bounds__(256) k_gn_partial(const float* __restrict__ x,
                                                    float* __restrict__ partials) {
  int blk = blockIdx.x;           // 64 groups * 16 parts
  int grp = blk >> 4;
  int part = blk & 15;
  const float* base = x + (size_t)grp * 262144 + (size_t)part * 16384;
  int t = threadIdx.x;
  float s = 0.f, s2 = 0.f;
  for (int i = 0; i < 16; ++i) {
    f32x4 v = *(const f32x4*)(base + (size_t)(i * 256 + t) * 4);
    s  += v[0] + v[1] + v[2] + v[3];
    s2 += v[0]*v[0] + v[1]*v[1] + v[2]*v[2] + v[3]*v[3];
  }
  for (int o = 32; o > 0; o >>= 1) { s += __shfl_down(s, o); s2 += __shfl_down(s2, o); }
  __shared__ float ls[4], ls2[4];
  int w = t >> 6;
  if ((t & 63) == 0) { ls[w] = s; ls2[w] = s2; }
  __syncthreads();
  if (t == 0) {
    partials[blk * 2] = ls[0] + ls[1] + ls[2] + ls[3];
    partials[blk * 2 + 1] = ls2[0] + ls2[1] + ls2[2] + ls2[3];
  }
}

// ---------------- K2: finalize stats + qkv weight -> bf16 + WqT ----------------
__global__ void __launch_bounds__(256) k_finalize(const float* __restrict__ partials,
                                                  float* __restrict__ stats,
                                                  const float* __restrict__ qkvw,
                                                  unsigned short* __restrict__ Wb,
                                                  unsigned short* __restrict__ WqT) {
  int bx = blockIdx.x, t = threadIdx.x;
  if (bx == 0) {
    if (t < 64) {
      float S = 0.f, S2 = 0.f;
      for (int i = 0; i < 16; ++i) { S += partials[(t * 16 + i) * 2]; S2 += partials[(t * 16 + i) * 2 + 1]; }
      float mu = S * (1.f / 262144.f);
      float var = S2 * (1.f / 262144.f) - mu * mu;
      stats[t * 2] = mu;
      stats[t * 2 + 1] = rsqrtf(var + 1e-5f);
    }
  } else if (bx <= 192) {
    int idx = (bx - 1) * 256 + t;               // float4 index, 49152 total
    f32x4 v = *(const f32x4*)(qkvw + (size_t)idx * 4);
    s16x4 o;
    for (int i = 0; i < 4; ++i) o[i] = (short)f2b(v[i]);
    *(s16x4*)(Wb + (size_t)idx * 4) = o;
  } else {
    // WqT[c][d] = qkvw[d][c], bf16, 256x256.  16 blocks (193..208).
    int bb = bx - 193;
    int c = bb * 16 + (t & 15);
    int d0 = (t >> 4) * 16;
    for (int i = 0; i < 16; ++i) {
      int d = d0 + i;
      WqT[(size_t)c * 256 + d] = f2b(qkvw[(size_t)d * 256 + c]);
    }
  }
}

// ---------------- K3: GroupNorm apply + transpose -> xnT[b][n][c] bf16 ----------------
__global__ void __launch_bounds__(256) k_norm_t(const float* __restrict__ x,
                                                const float* __restrict__ stats,
                                                const float* __restrict__ gamma,
                                                const float* __restrict__ beta,
                                                unsigned short* __restrict__ xnT) {
  int blk = blockIdx.x;           // 16 b * 256 tiles
  int b = blk >> 8;
  int tile = blk & 255;
  int ct = tile >> 6;
  int nt = tile & 63;
  int c0 = ct * 64, n0 = nt * 64;
  __shared__ float T[64][65];
  int t = threadIdx.x;
  float mu = stats[(b * 4 + ct) * 2];
  float rs = stats[(b * 4 + ct) * 2 + 1];
  int cl = t >> 2, q4 = t & 3;
  float sc = gamma[c0 + cl] * rs;
  float off = beta[c0 + cl] - mu * sc;
  const float* xr = x + ((size_t)b * 256 + c0 + cl) * 4096 + n0;
  for (int p = 0; p < 4; ++p) {
    int col = p * 16 + q4 * 4;
    f32x4 v = *(const f32x4*)(xr + col);
    for (int i = 0; i < 4; ++i) T[cl][col + i] = v[i] * sc + off;
  }
  __syncthreads();
  int nl = t >> 2, cc = t & 3;
  u16x8 o0, o1;
  for (int i = 0; i < 8; ++i) o0[i] = f2b(T[cc * 16 + i][nl]);
  for (int i = 0; i < 8; ++i) o1[i] = f2b(T[cc * 16 + 8 + i][nl]);
  unsigned short* dst = xnT + ((size_t)b * 4096 + n0 + nl) * 256 + c0 + cc * 16;
  *(u16x8*)dst = o0;
  *(u16x8*)(dst + 8) = o1;
}

// ---------------- K4: fused kv-GEMM + exp + att accumulation ----------------
// grid: x = 64 ((b<<2)|ns), y = 8 (h). 8 head-blocks of one (b,ns) share an XCD
// (linear ids differ by 64 == 0 mod 8) -> xnT slice served from L2.
// launch_bounds(256,2): grid = 2 blocks/CU; allow ~256 VGPR so af[2][8] (64 VGPR)
// stays resident and bfr is rolling-prefetched one chunk ahead (~180 VGPR live).
__global__ void __launch_bounds__(256, 2) k_attfused(const unsigned short* __restrict__ Wb,
                                                     const unsigned short* __restrict__ xnT,
                                                     float* __restrict__ attg,
                                                     float* __restrict__ rsums) {
  const int bx = blockIdx.x;
  const int b = bx >> 2, ns = bx & 3, h = blockIdx.y;
  const int hb = b * 8 + h;
  const int t = threadIdx.x;
  const int wave = t >> 6, lane = t & 63;
  const int g = lane >> 4, r = lane & 15;
  const int rh = wave >> 1;             // 0 = k-rows (d), 1 = v-rows (e)
  const int ch = wave & 1;              // n-col half of the 64-chunk
  __shared__ unsigned short PL[2][32][72];   // [d][n-chunk64], 144B rows (16B-aligned)
  __shared__ unsigned short VL[2][32][72];   // [e][n-chunk64]

  // preload W A-frags: k rows at qkv 256+h*32, v rows at 512+h*32
  const unsigned short* Wrow = Wb + (size_t)(256 + rh * 256 + h * 32) * 256;
  bf16x8 af[2][8];
#pragma unroll
  for (int rt = 0; rt < 2; ++rt)
#pragma unroll
    for (int kt = 0; kt < 8; ++kt)
      af[rt][kt] = *(const bf16x8*)(Wrow + (size_t)(rt * 16 + r) * 256 + kt * 32 + 8 * g);

  const unsigned short* Xb = xnT + ((size_t)b * 4096 + ns * 1024 + ch * 32 + r) * 256 + 8 * g;
  f32x4 attacc = {0.f, 0.f, 0.f, 0.f};
  float rs[2][4] = {{0.f,0.f,0.f,0.f},{0.f,0.f,0.f,0.f}};

  // ---- prime chunk 0 B-frags ----
  bf16x8 bfr[8][2];
#pragma unroll
  for (int kt = 0; kt < 8; ++kt) {
    bfr[kt][0] = *(const bf16x8*)(Xb + kt * 32);
    bfr[kt][1] = *(const bf16x8*)(Xb + (size_t)(16 * 256) + kt * 32);
  }

  for (int c = 0; c < 16; ++c) {
    const int cur = c & 1;
    // next chunk base (wraps at c=15: harmless reload of chunk 0, never used)
    const unsigned short* Xn = Xb + (size_t)(((c + 1) & 15) * 64) * 256;
    f32x4 sacc[2][2] = {};
    __builtin_amdgcn_s_setprio(1);
#pragma unroll
    for (int kt = 0; kt < 8; ++kt) {
      bf16x8 b0 = bfr[kt][0], b1 = bfr[kt][1];
      // rolling prefetch: load (c+1, kt) right after (c, kt)'s last use is queued
      bfr[kt][0] = *(const bf16x8*)(Xn + kt * 32);
      bfr[kt][1] = *(const bf16x8*)(Xn + (size_t)(16 * 256) + kt * 32);
      sacc[0][0] = __builtin_amdgcn_mfma_f32_16x16x32_bf16(af[0][kt], b0, sacc[0][0], 0, 0, 0);
      sacc[0][1] = __builtin_amdgcn_mfma_f32_16x16x32_bf16(af[0][kt], b1, sacc[0][1], 0, 0, 0);
      sacc[1][0] = __builtin_amdgcn_mfma_f32_16x16x32_bf16(af[1][kt], b0, sacc[1][0], 0, 0, 0);
      sacc[1][1] = __builtin_amdgcn_mfma_f32_16x16x32_bf16(af[1][kt], b1, sacc[1][1], 0, 0, 0);
    }
    __builtin_amdgcn_s_setprio(0);
    // ---- exp (k) / passthrough (v) -> PL/VL bf16, C-layout scatter ----
    if (rh == 0) {
#pragma unroll
      for (int rt = 0; rt < 2; ++rt)
#pragma unroll
        for (int ct = 0; ct < 2; ++ct)
#pragma unroll
          for (int reg = 0; reg < 4; ++reg) {
            float e = __expf(sacc[rt][ct][reg]);
            rs[rt][reg] += e;
            PL[cur][rt * 16 + 4 * g + reg][ch * 32 + ct * 16 + r] = f2b(e);
          }
    } else {
#pragma unroll
      for (int rt = 0; rt < 2; ++rt)
#pragma unroll
        for (int ct = 0; ct < 2; ++ct)
#pragma unroll
          for (int reg = 0; reg < 4; ++reg)
            VL[cur][rt * 16 + 4 * g + reg][ch * 32 + ct * 16 + r] = f2b(sacc[rt][ct][reg]);
    }
    __syncthreads();
    // ---- att quadrant (rh,ch) += P . V^T over 64 n ----
#pragma unroll
    for (int ks = 0; ks < 2; ++ks) {
      bf16x8 pa = *(const bf16x8*)&PL[cur][rh * 16 + r][ks * 32 + 8 * g];
      bf16x8 vb = *(const bf16x8*)&VL[cur][ch * 16 + r][ks * 32 + 8 * g];
      attacc = __builtin_amdgcn_mfma_f32_16x16x32_bf16(pa, vb, attacc, 0, 0, 0);
    }
  }
  // ---- global accumulate ----
  float* ab = attg + (size_t)hb * 1024;
#pragma unroll
  for (int reg = 0; reg < 4; ++reg)
    atomicAdd(&ab[(rh * 16 + 4 * g + reg) * 32 + ch * 16 + r], attacc[reg]);
  if (rh == 0) {
#pragma unroll
    for (int rt = 0; rt < 2; ++rt)
#pragma unroll
      for (int reg = 0; reg < 4; ++reg) {
        float v = rs[rt][reg];
        v += __shfl_xor(v, 1); v += __shfl_xor(v, 2);
        v += __shfl_xor(v, 4); v += __shfl_xor(v, 8);
        if (r == 0) atomicAdd(&rsums[hb * 32 + rt * 16 + 4 * g + reg], v);
      }
  }
}

// ---------------- gemm_bt: C[M][N] = A[M][256].B[N][256]^T (small M2 GEMM) ----------
template<bool OUT_BF16, bool ADD_BIAS>
__global__ void __launch_bounds__(256)
k_gemm_bt(const unsigned short* __restrict__ A,
          const unsigned short* __restrict__ B,
          void* __restrict__ Cv,
          const float* __restrict__ bias,
          long sA, long sB, long sC, int ldc) {
  __shared__ unsigned short LA[128][32];
  __shared__ unsigned short LB[128][32];
  const int t = threadIdx.x;
  const unsigned short* Ab = A + (size_t)blockIdx.z * sA + (size_t)blockIdx.x * 128 * 256;
  const unsigned short* Bb = B + (size_t)blockIdx.z * sB + (size_t)blockIdx.y * 128 * 256;
  const int wave = t >> 6, lane = t & 63;
  const int wm = wave >> 1, wn = wave & 1;
  const int g = lane >> 4, r = lane & 15;
  const int rA = t >> 2, sslot = t & 3;
  const int ws0 = 8 * (sslot ^ (rA & 3));
  const int rslot = 8 * (g ^ (r & 3));
  const unsigned short* ag = Ab + (size_t)rA * 256 + 8 * sslot;
  const unsigned short* bg = Bb + (size_t)rA * 256 + 8 * sslot;
  u16x8 pa0 = *(const u16x8*)(ag);
  u16x8 pa1 = *(const u16x8*)(ag + 64 * 256);
  u16x8 pb0 = *(const u16x8*)(bg);
  u16x8 pb1 = *(const u16x8*)(bg + 64 * 256);
  f32x4 acc[4][4] = {};
  for (int kt = 0; kt < 8; ++kt) {
    if (kt) __syncthreads();
    *(u16x8*)&LA[rA][ws0] = pa0;  *(u16x8*)&LA[rA + 64][ws0] = pa1;
    *(u16x8*)&LB[rA][ws0] = pb0;  *(u16x8*)&LB[rA + 64][ws0] = pb1;
    __syncthreads();
    if (kt < 7) {
      int off = (kt + 1) * 32;
      pa0 = *(const u16x8*)(ag + off);  pa1 = *(const u16x8*)(ag + 64 * 256 + off);
      pb0 = *(const u16x8*)(bg + off);  pb1 = *(const u16x8*)(bg + 64 * 256 + off);
    }
    bf16x8 af[4], bfr[4];
    for (int i = 0; i < 4; ++i) {
      af[i]  = *(const bf16x8*)&LA[wm * 64 + i * 16 + r][rslot];
      bfr[i] = *(const bf16x8*)&LB[wn * 64 + i * 16 + r][rslot];
    }
    for (int mi = 0; mi < 4; ++mi)
      for (int ni = 0; ni < 4; ++ni)
        acc[mi][ni] = __builtin_amdgcn_mfma_f32_16x16x32_bf16(af[mi], bfr[ni], acc[mi][ni], 0, 0, 0);
  }
  const int m0 = blockIdx.x * 128 + wm * 64;
  const int n0 = blockIdx.y * 128 + wn * 64;
  if (OUT_BF16) {
    unsigned short* C = (unsigned short*)Cv + (size_t)blockIdx.z * sC;
    for (int mi = 0; mi < 4; ++mi)
      for (int ni = 0; ni < 4; ++ni) {
        int row = m0 + mi * 16 + 4 * g;
        int col = n0 + ni * 16 + r;
        for (int reg = 0; reg < 4; ++reg)
          C[(size_t)(row + reg) * ldc + col] = f2b(acc[mi][ni][reg]);
      }
  } else {
    float* C = (float*)Cv + (size_t)blockIdx.z * sC;
    for (int mi = 0; mi < 4; ++mi)
      for (int ni = 0; ni < 4; ++ni) {
        int row = m0 + mi * 16 + 4 * g;
        int col = n0 + ni * 16 + r;
        for (int reg = 0; reg < 4; ++reg) {
          float v = acc[mi][ni][reg];
          if (ADD_BIAS) v += bias[row + reg];
          C[(size_t)(row + reg) * ldc + col] = v;
        }
      }
  }
}

// ---------------- K5: P[b][o][hd] = sum_e proj[o][he] * attg[h,d,e]/rsum[d] ----------------
__global__ void __launch_bounds__(256) k_makeM(const float* __restrict__ attg,
                                               const float* __restrict__ rsums,
                                               const float* __restrict__ projw,
                                               unsigned short* __restrict__ Mb) {
  int blk = blockIdx.x;           // 16*8 (b,h)
  int b = blk >> 3, h = blk & 7;
  __shared__ float attL[32][33];
  __shared__ float invs[32];
  int t = threadIdx.x;
  if (t < 32) invs[t] = 1.f / rsums[blk * 32 + t];
  const float* asrc = attg + (size_t)blk * 1024;
  {
    f32x4 v = *(const f32x4*)(asrc + (size_t)t * 4);
    int idx = t * 4;
    for (int i = 0; i < 4; ++i) attL[(idx + i) >> 5][(idx + i) & 31] = v[i];
  }
  __syncthreads();
  float pw[32];
  const float* ps = projw + (size_t)t * 256 + h * 32;
  for (int i = 0; i < 8; ++i) {
    f32x4 v = *(const f32x4*)(ps + i * 4);
    pw[i * 4 + 0] = v[0]; pw[i * 4 + 1] = v[1]; pw[i * 4 + 2] = v[2]; pw[i * 4 + 3] = v[3];
  }
  unsigned short* dst = Mb + ((size_t)b * 256 + t) * 256 + h * 32;
  for (int dd = 0; dd < 32; ++dd) {
    float s = 0.f;
    for (int e = 0; e < 32; ++e) s += pw[e] * attL[dd][e];
    dst[dd] = f2b(s * invs[dd]);
  }
}

// ---------------- K7: out[b][o][nt*64..] = M2[b] . xnT^T + bias  (M=256, N=64) ----------
__global__ void __launch_bounds__(256) k_gemm_final(const unsigned short* __restrict__ M2,
                                                    const unsigned short* __restrict__ xnT,
                                                    float* __restrict__ out,
                                                    const float* __restrict__ bias) {
  const int nt = blockIdx.x, b = blockIdx.y;
  const unsigned short* Ab = M2 + (size_t)b * 65536;
  const unsigned short* Bb = xnT + ((size_t)b * 4096 + nt * 64) * 256;
  float* Cb = out + (size_t)b * 1048576 + (size_t)nt * 64;
  __shared__ unsigned short LB[2][64][32];
  const int t = threadIdx.x;
  const int wave = t >> 6, lane = t & 63, g = lane >> 4, r = lane & 15;
  const int srow = t >> 2, sslot = t & 3;
  const int ws0 = 8 * (sslot ^ (srow & 3));
  const int rslot = 8 * (g ^ (r & 3));
  const unsigned short* bg = Bb + (size_t)srow * 256 + 8 * sslot;
  const unsigned short* ar = Ab + (size_t)(wave * 64 + r) * 256 + 8 * g;
  u16x8 pb = *(const u16x8*)bg;
  f32x4 acc[4][4] = {};
  for (int kt = 0; kt < 8; ++kt) {
    const int cur = kt & 1;
    *(u16x8*)&LB[cur][srow][ws0] = pb;
    __syncthreads();
    if (kt < 7) pb = *(const u16x8*)(bg + (kt + 1) * 32);
    bf16x8 af[4], bfr[4];
#pragma unroll
    for (int mi = 0; mi < 4; ++mi)
      af[mi] = *(const bf16x8*)(ar + (size_t)(mi * 16) * 256 + kt * 32);
#pragma unroll
    for (int ni = 0; ni < 4; ++ni)
      bfr[ni] = *(const bf16x8*)&LB[cur][ni * 16 + r][rslot];
#pragma unroll
    for (int mi = 0; mi < 4; ++mi)
#pragma unroll
      for (int ni = 0; ni < 4; ++ni)
        acc[mi][ni] = __builtin_amdgcn_mfma_f32_16x16x32_bf16(af[mi], bfr[ni], acc[mi][ni], 0, 0, 0);
  }
#pragma unroll
  for (int mi = 0; mi < 4; ++mi) {
    const int row = wave * 64 + mi * 16 + 4 * g;
#pragma unroll
    for (int ni = 0; ni < 4; ++ni)
#pragma unroll
      for (int reg = 0; reg < 4; ++reg)
        Cb[(size_t)(row + reg) * 4096 + ni * 16 + r] = acc[mi][ni][reg] + bias[row + reg];
  }
}

extern "C" void kernel_launch(void* const* d_in, const int* in_sizes, int n_in,
                              void* d_out, int out_size, void* d_ws, size_t ws_size,
                              hipStream_t stream) {
  (void)in_sizes; (void)n_in; (void)out_size; (void)ws_size;
  const float* x     = (const float*)d_in[0];
  const float* gn_w  = (const float*)d_in[1];
  const float* gn_b  = (const float*)d_in[2];
  const float* qkvw  = (const float*)d_in[3];
  const float* projw = (const float*)d_in[4];
  const float* projb = (const float*)d_in[5];

  char* ws = (char*)d_ws;
  float*          partials = (float*)(ws);                       //   8 KB
  float*          stats    = (float*)(ws + 8192);                //  512 B
  unsigned short* Wb       = (unsigned short*)(ws + 16384);      //  384 KB (768x256)
  unsigned short* Mb       = (unsigned short*)(ws + 409600);     //    2 MB (P: 16x256x256)
  float*          attg     = (float*)(ws + 2506752);             //  512 KB (16x8x32x32)
  float*          rsums    = (float*)(ws + 3031040);             //   16 KB (16x8x32)
  unsigned short* WqT      = (unsigned short*)(ws + 3047424);    //  128 KB (256x256)
  unsigned short* M2       = (unsigned short*)(ws + 3178496);    //    2 MB (16x256x256)
  unsigned short* xnT      = (unsigned short*)(ws + 8388608);    //   32 MB (16x4096x256)

  k_gn_partial<<<1024, 256, 0, stream>>>(x, partials);
  k_finalize<<<209, 256, 0, stream>>>(partials, stats, qkvw, Wb, WqT);
  k_norm_t<<<4096, 256, 0, stream>>>(x, stats, gn_w, gn_b, xnT);
  (void)hipMemsetAsync(attg, 0, 540672, stream);   // attg + rsums (contiguous)
  k_attfused<<<dim3(64, 8), 256, 0, stream>>>(Wb, xnT, attg, rsums);
  k_makeM<<<128, 256, 0, stream>>>(attg, rsums, projw, Mb);
  // M2[b][256][256] = P . WqT^T  (= P.Wq)
  k_gemm_bt<true, false><<<dim3(2, 2, 16), 256, 0, stream>>>(
      Mb, WqT, (void*)M2, nullptr, 65536L, 0L, 65536L, 256);
  // out[b][256][4096] = M2 . xnT^T + bias
  k_gemm_final<<<dim3(64, 16), 256, 0, stream>>>(M2, xnT, (float*)d_out, projb);
}

// Round 6
// 205.738 us; speedup vs baseline: 1.2147x; 1.1664x over previous
//
#include <hip/hip_runtime.h>
#include <hip/hip_bf16.h>

// B=16, C=256, H=W=64 (N=4096), HEADS=8, HD=32, GROUPS=4, EPS=1e-5
// Pipeline:
//  K1 gn_partial : partial sum/sumsq per (b,g,part)
//  K2 finalize   : mu/rstd + qkv_weight->bf16 + WqT (bf16 [c][d])
//  K3 norm_t     : xnT[b][n][c] = GN(x) bf16
//  K4 attfused   : per (b,h,ns): stage X chunk to LDS (global_load_lds),
//                  S=Wkv_h.xn^T (W in regs), exp, att += P.V^T (atomics)
//  K5 makeM      : P[b][o][hd] = sum_e proj[o][he] attg[h,d,e]/rsum  (bf16)
//  K6 gemm_bt    : M2[b][o][c] = P . WqT^T   (= P.Wq)                (bf16)
//  K7 gemm_final : out[b][o][n] = M2 . xnT^T + bias  (M=256 x N=64 tiles)
// Folding: proj@out = (P@Wq)@xn = M2@xn ; kv never materialized to HBM.

typedef __attribute__((ext_vector_type(4))) float f32x4;
typedef __attribute__((ext_vector_type(8))) short bf16x8;
typedef __attribute__((ext_vector_type(4))) short s16x4;
typedef __attribute__((ext_vector_type(8))) unsigned short u16x8;

__device__ inline float b2f(unsigned short u) {
  unsigned int x = ((unsigned int)u) << 16;
  float f; __builtin_memcpy(&f, &x, 4); return f;
}
__device__ inline unsigned short f2b(float f) {
  unsigned int x; __builtin_memcpy(&x, &f, 4);
  x += 0x7FFFu + ((x >> 16) & 1u);            // RNE
  return (unsigned short)(x >> 16);
}

// ---------------- K1: GN partial sums ----------------
__global__ void __launch_bounds__(256) k_gn_partial(const float* __restrict__ x,
                                                    float* __restrict__ partials) {
  int blk = blockIdx.x;           // 64 groups * 16 parts
  int grp = blk >> 4;
  int part = blk & 15;
  const float* base = x + (size_t)grp * 262144 + (size_t)part * 16384;
  int t = threadIdx.x;
  float s = 0.f, s2 = 0.f;
  for (int i = 0; i < 16; ++i) {
    f32x4 v = *(const f32x4*)(base + (size_t)(i * 256 + t) * 4);
    s  += v[0] + v[1] + v[2] + v[3];
    s2 += v[0]*v[0] + v[1]*v[1] + v[2]*v[2] + v[3]*v[3];
  }
  for (int o = 32; o > 0; o >>= 1) { s += __shfl_down(s, o); s2 += __shfl_down(s2, o); }
  __shared__ float ls[4], ls2[4];
  int w = t >> 6;
  if ((t & 63) == 0) { ls[w] = s; ls2[w] = s2; }
  __syncthreads();
  if (t == 0) {
    partials[blk * 2] = ls[0] + ls[1] + ls[2] + ls[3];
    partials[blk * 2 + 1] = ls2[0] + ls2[1] + ls2[2] + ls2[3];
  }
}

// ---------------- K2: finalize stats + qkv weight -> bf16 + WqT ----------------
__global__ void __launch_bounds__(256) k_finalize(const float* __restrict__ partials,
                                                  float* __restrict__ stats,
                                                  const float* __restrict__ qkvw,
                                                  unsigned short* __restrict__ Wb,
                                                  unsigned short* __restrict__ WqT) {
  int bx = blockIdx.x, t = threadIdx.x;
  if (bx == 0) {
    if (t < 64) {
      float S = 0.f, S2 = 0.f;
      for (int i = 0; i < 16; ++i) { S += partials[(t * 16 + i) * 2]; S2 += partials[(t * 16 + i) * 2 + 1]; }
      float mu = S * (1.f / 262144.f);
      float var = S2 * (1.f / 262144.f) - mu * mu;
      stats[t * 2] = mu;
      stats[t * 2 + 1] = rsqrtf(var + 1e-5f);
    }
  } else if (bx <= 192) {
    int idx = (bx - 1) * 256 + t;               // float4 index, 49152 total
    f32x4 v = *(const f32x4*)(qkvw + (size_t)idx * 4);
    s16x4 o;
    for (int i = 0; i < 4; ++i) o[i] = (short)f2b(v[i]);
    *(s16x4*)(Wb + (size_t)idx * 4) = o;
  } else {
    // WqT[c][d] = qkvw[d][c], bf16, 256x256.  16 blocks (193..208).
    int bb = bx - 193;
    int c = bb * 16 + (t & 15);
    int d0 = (t >> 4) * 16;
    for (int i = 0; i < 16; ++i) {
      int d = d0 + i;
      WqT[(size_t)c * 256 + d] = f2b(qkvw[(size_t)d * 256 + c]);
    }
  }
}

// ---------------- K3: GroupNorm apply + transpose -> xnT[b][n][c] bf16 ----------------
__global__ void __launch_bounds__(256) k_norm_t(const float* __restrict__ x,
                                                const float* __restrict__ stats,
                                                const float* __restrict__ gamma,
                                                const float* __restrict__ beta,
                                                unsigned short* __restrict__ xnT) {
  int blk = blockIdx.x;           // 16 b * 256 tiles
  int b = blk >> 8;
  int tile = blk & 255;
  int ct = tile >> 6;
  int nt = tile & 63;
  int c0 = ct * 64, n0 = nt * 64;
  __shared__ float T[64][65];
  int t = threadIdx.x;
  float mu = stats[(b * 4 + ct) * 2];
  float rs = stats[(b * 4 + ct) * 2 + 1];
  int cl = t >> 2, q4 = t & 3;
  float sc = gamma[c0 + cl] * rs;
  float off = beta[c0 + cl] - mu * sc;
  const float* xr = x + ((size_t)b * 256 + c0 + cl) * 4096 + n0;
  for (int p = 0; p < 4; ++p) {
    int col = p * 16 + q4 * 4;
    f32x4 v = *(const f32x4*)(xr + col);
    for (int i = 0; i < 4; ++i) T[cl][col + i] = v[i] * sc + off;
  }
  __syncthreads();
  int nl = t >> 2, cc = t & 3;
  u16x8 o0, o1;
  for (int i = 0; i < 8; ++i) o0[i] = f2b(T[cc * 16 + i][nl]);
  for (int i = 0; i < 8; ++i) o1[i] = f2b(T[cc * 16 + 8 + i][nl]);
  unsigned short* dst = xnT + ((size_t)b * 4096 + n0 + nl) * 256 + c0 + cc * 16;
  *(u16x8*)dst = o0;
  *(u16x8*)(dst + 8) = o1;
}

// ---------------- K4: fused kv-GEMM + exp + att accumulation ----------------
// LDS-staged X (single buffer, global_load_lds w=16, pre-swizzled source per
// rule "both-sides-or-neither"): LDS(row, s) = X[row][s ^ (row&7)] (16B slots).
// Frags pinned into regs by barrier A; stage(c+1) overlaps reg-only S-MFMAs.
__global__ void __launch_bounds__(256, 2) k_attfused(const unsigned short* __restrict__ Wb,
                                                     const unsigned short* __restrict__ xnT,
                                                     float* __restrict__ attg,
                                                     float* __restrict__ rsums) {
  const int bx = blockIdx.x;
  const int b = bx >> 2, ns = bx & 3, h = blockIdx.y;
  const int hb = b * 8 + h;
  const int t = threadIdx.x;
  const int wave = t >> 6, lane = t & 63;
  const int g = lane >> 4, r = lane & 15;
  const int rh = wave >> 1;             // 0 = k-rows (d), 1 = v-rows (e)
  const int ch = wave & 1;              // n-col half of the 64-chunk
  __shared__ unsigned short XL[64][256];     // 32 KB, one 64-n chunk, K=256
  __shared__ unsigned short PL[2][32][72];   // exp(k) tiles
  __shared__ unsigned short VL[2][32][72];   // v tiles

  // preload W A-frags: k rows at qkv 256+h*32, v rows at 512+h*32 (resident)
  const unsigned short* Wrow = Wb + (size_t)(256 + rh * 256 + h * 32) * 256;
  bf16x8 af[2][8];
#pragma unroll
  for (int rt = 0; rt < 2; ++rt)
#pragma unroll
    for (int kt = 0; kt < 8; ++kt)
      af[rt][kt] = *(const bf16x8*)(Wrow + (size_t)(rt * 16 + r) * 256 + kt * 32 + 8 * g);

  const unsigned short* slice = xnT + ((size_t)b * 4096 + ns * 1024) * 256;
  // staging geometry: thread t, load i -> LDS bytes [i*4096 + t*16]
  //   row = i*8 + (t>>5), phys 16B-slot = t&31; source col slot = (t&31)^(t>>5)
  const int swz = t >> 5;
  const unsigned short* gstage = slice + (size_t)swz * 256 + ((t & 31) ^ swz) * 8;
  char* lstage = (char*)&XL[0][0] + ((t >> 6) << 10);
#pragma unroll
  for (int i = 0; i < 8; ++i)
    __builtin_amdgcn_global_load_lds((const void*)(gstage + (size_t)(i * 8) * 256),
                                     (void*)(lstage + i * 4096), 16, 0, 0);

  f32x4 attacc = {0.f, 0.f, 0.f, 0.f};
  float rs[2][4] = {{0.f,0.f,0.f,0.f},{0.f,0.f,0.f,0.f}};
  const char* xl0 = (const char*)&XL[0][0];
  __syncthreads();                           // chunk 0 landed (vmcnt drained)

  for (int c = 0; c < 16; ++c) {
    const int cur = c & 1;
    // ---- 1) B-frags from XL (swizzled read) ----
    bf16x8 bfr[8][2];
#pragma unroll
    for (int kt = 0; kt < 8; ++kt)
#pragma unroll
      for (int ct = 0; ct < 2; ++ct) {
        const int row = ch * 32 + ct * 16 + r;
        const int slot = (kt * 4 + g) ^ (r & 7);
        bfr[kt][ct] = *(const bf16x8*)(xl0 + row * 512 + slot * 16);
      }
    __syncthreads();                         // A: frags in regs; XL reusable
    // ---- 2) stage chunk c+1 (DMA, overlaps MFMAs) ----
    if (c < 15) {
      const unsigned short* gs = gstage + (size_t)(c + 1) * 64 * 256;
#pragma unroll
      for (int i = 0; i < 8; ++i)
        __builtin_amdgcn_global_load_lds((const void*)(gs + (size_t)(i * 8) * 256),
                                         (void*)(lstage + i * 4096), 16, 0, 0);
    }
    // ---- 3) S(32x32 per wave) = W . xn^T over K=256, reg-only ----
    f32x4 sacc[2][2] = {};
    __builtin_amdgcn_s_setprio(1);
#pragma unroll
    for (int kt = 0; kt < 8; ++kt) {
      sacc[0][0] = __builtin_amdgcn_mfma_f32_16x16x32_bf16(af[0][kt], bfr[kt][0], sacc[0][0], 0, 0, 0);
      sacc[0][1] = __builtin_amdgcn_mfma_f32_16x16x32_bf16(af[0][kt], bfr[kt][1], sacc[0][1], 0, 0, 0);
      sacc[1][0] = __builtin_amdgcn_mfma_f32_16x16x32_bf16(af[1][kt], bfr[kt][0], sacc[1][0], 0, 0, 0);
      sacc[1][1] = __builtin_amdgcn_mfma_f32_16x16x32_bf16(af[1][kt], bfr[kt][1], sacc[1][1], 0, 0, 0);
    }
    __builtin_amdgcn_s_setprio(0);
    // ---- 4) exp (k) / passthrough (v) -> PL/VL[cur] ----
    if (rh == 0) {
#pragma unroll
      for (int rt = 0; rt < 2; ++rt)
#pragma unroll
        for (int ct = 0; ct < 2; ++ct)
#pragma unroll
          for (int reg = 0; reg < 4; ++reg) {
            float e = __expf(sacc[rt][ct][reg]);
            rs[rt][reg] += e;
            PL[cur][rt * 16 + 4 * g + reg][ch * 32 + ct * 16 + r] = f2b(e);
          }
    } else {
#pragma unroll
      for (int rt = 0; rt < 2; ++rt)
#pragma unroll
        for (int ct = 0; ct < 2; ++ct)
#pragma unroll
          for (int reg = 0; reg < 4; ++reg)
            VL[cur][rt * 16 + 4 * g + reg][ch * 32 + ct * 16 + r] = f2b(sacc[rt][ct][reg]);
    }
    __syncthreads();                         // B: PL/VL ready; XL = chunk c+1
    // ---- 5) att quadrant (rh,ch) += P . V^T over 64 n ----
#pragma unroll
    for (int ks = 0; ks < 2; ++ks) {
      bf16x8 pa = *(const bf16x8*)&PL[cur][rh * 16 + r][ks * 32 + 8 * g];
      bf16x8 vb = *(const bf16x8*)&VL[cur][ch * 16 + r][ks * 32 + 8 * g];
      attacc = __builtin_amdgcn_mfma_f32_16x16x32_bf16(pa, vb, attacc, 0, 0, 0);
    }
  }
  // ---- global accumulate ----
  float* ab = attg + (size_t)hb * 1024;
#pragma unroll
  for (int reg = 0; reg < 4; ++reg)
    atomicAdd(&ab[(rh * 16 + 4 * g + reg) * 32 + ch * 16 + r], attacc[reg]);
  if (rh == 0) {
#pragma unroll
    for (int rt = 0; rt < 2; ++rt)
#pragma unroll
      for (int reg = 0; reg < 4; ++reg) {
        float v = rs[rt][reg];
        v += __shfl_xor(v, 1); v += __shfl_xor(v, 2);
        v += __shfl_xor(v, 4); v += __shfl_xor(v, 8);
        if (r == 0) atomicAdd(&rsums[hb * 32 + rt * 16 + 4 * g + reg], v);
      }
  }
}

// ---------------- gemm_bt: C[M][N] = A[M][256].B[N][256]^T (small M2 GEMM) ----------
template<bool OUT_BF16, bool ADD_BIAS>
__global__ void __launch_bounds__(256)
k_gemm_bt(const unsigned short* __restrict__ A,
          const unsigned short* __restrict__ B,
          void* __restrict__ Cv,
          const float* __restrict__ bias,
          long sA, long sB, long sC, int ldc) {
  __shared__ unsigned short LA[128][32];
  __shared__ unsigned short LB[128][32];
  const int t = threadIdx.x;
  const unsigned short* Ab = A + (size_t)blockIdx.z * sA + (size_t)blockIdx.x * 128 * 256;
  const unsigned short* Bb = B + (size_t)blockIdx.z * sB + (size_t)blockIdx.y * 128 * 256;
  const int wave = t >> 6, lane = t & 63;
  const int wm = wave >> 1, wn = wave & 1;
  const int g = lane >> 4, r = lane & 15;
  const int rA = t >> 2, sslot = t & 3;
  const int ws0 = 8 * (sslot ^ (rA & 3));
  const int rslot = 8 * (g ^ (r & 3));
  const unsigned short* ag = Ab + (size_t)rA * 256 + 8 * sslot;
  const unsigned short* bg = Bb + (size_t)rA * 256 + 8 * sslot;
  u16x8 pa0 = *(const u16x8*)(ag);
  u16x8 pa1 = *(const u16x8*)(ag + 64 * 256);
  u16x8 pb0 = *(const u16x8*)(bg);
  u16x8 pb1 = *(const u16x8*)(bg + 64 * 256);
  f32x4 acc[4][4] = {};
  for (int kt = 0; kt < 8; ++kt) {
    if (kt) __syncthreads();
    *(u16x8*)&LA[rA][ws0] = pa0;  *(u16x8*)&LA[rA + 64][ws0] = pa1;
    *(u16x8*)&LB[rA][ws0] = pb0;  *(u16x8*)&LB[rA + 64][ws0] = pb1;
    __syncthreads();
    if (kt < 7) {
      int off = (kt + 1) * 32;
      pa0 = *(const u16x8*)(ag + off);  pa1 = *(const u16x8*)(ag + 64 * 256 + off);
      pb0 = *(const u16x8*)(bg + off);  pb1 = *(const u16x8*)(bg + 64 * 256 + off);
    }
    bf16x8 af[4], bfr[4];
    for (int i = 0; i < 4; ++i) {
      af[i]  = *(const bf16x8*)&LA[wm * 64 + i * 16 + r][rslot];
      bfr[i] = *(const bf16x8*)&LB[wn * 64 + i * 16 + r][rslot];
    }
    for (int mi = 0; mi < 4; ++mi)
      for (int ni = 0; ni < 4; ++ni)
        acc[mi][ni] = __builtin_amdgcn_mfma_f32_16x16x32_bf16(af[mi], bfr[ni], acc[mi][ni], 0, 0, 0);
  }
  const int m0 = blockIdx.x * 128 + wm * 64;
  const int n0 = blockIdx.y * 128 + wn * 64;
  if (OUT_BF16) {
    unsigned short* C = (unsigned short*)Cv + (size_t)blockIdx.z * sC;
    for (int mi = 0; mi < 4; ++mi)
      for (int ni = 0; ni < 4; ++ni) {
        int row = m0 + mi * 16 + 4 * g;
        int col = n0 + ni * 16 + r;
        for (int reg = 0; reg < 4; ++reg)
          C[(size_t)(row + reg) * ldc + col] = f2b(acc[mi][ni][reg]);
      }
  } else {
    float* C = (float*)Cv + (size_t)blockIdx.z * sC;
    for (int mi = 0; mi < 4; ++mi)
      for (int ni = 0; ni < 4; ++ni) {
        int row = m0 + mi * 16 + 4 * g;
        int col = n0 + ni * 16 + r;
        for (int reg = 0; reg < 4; ++reg) {
          float v = acc[mi][ni][reg];
          if (ADD_BIAS) v += bias[row + reg];
          C[(size_t)(row + reg) * ldc + col] = v;
        }
      }
  }
}

// ---------------- K5: P[b][o][hd] = sum_e proj[o][he] * attg[h,d,e]/rsum[d] ----------------
__global__ void __launch_bounds__(256) k_makeM(const float* __restrict__ attg,
                                               const float* __restrict__ rsums,
                                               const float* __restrict__ projw,
                                               unsigned short* __restrict__ Mb) {
  int blk = blockIdx.x;           // 16*8 (b,h)
  int b = blk >> 3, h = blk & 7;
  __shared__ float attL[32][33];
  __shared__ float invs[32];
  int t = threadIdx.x;
  if (t < 32) invs[t] = 1.f / rsums[blk * 32 + t];
  const float* asrc = attg + (size_t)blk * 1024;
  {
    f32x4 v = *(const f32x4*)(asrc + (size_t)t * 4);
    int idx = t * 4;
    for (int i = 0; i < 4; ++i) attL[(idx + i) >> 5][(idx + i) & 31] = v[i];
  }
  __syncthreads();
  float pw[32];
  const float* ps = projw + (size_t)t * 256 + h * 32;
  for (int i = 0; i < 8; ++i) {
    f32x4 v = *(const f32x4*)(ps + i * 4);
    pw[i * 4 + 0] = v[0]; pw[i * 4 + 1] = v[1]; pw[i * 4 + 2] = v[2]; pw[i * 4 + 3] = v[3];
  }
  unsigned short* dst = Mb + ((size_t)b * 256 + t) * 256 + h * 32;
  for (int dd = 0; dd < 32; ++dd) {
    float s = 0.f;
    for (int e = 0; e < 32; ++e) s += pw[e] * attL[dd][e];
    dst[dd] = f2b(s * invs[dd]);
  }
}

// ---------------- K7: out[b][o][nt*64..] = M2[b] . xnT^T + bias  (M=256, N=64) ----------
__global__ void __launch_bounds__(256) k_gemm_final(const unsigned short* __restrict__ M2,
                                                    const unsigned short* __restrict__ xnT,
                                                    float* __restrict__ out,
                                                    const float* __restrict__ bias) {
  const int nt = blockIdx.x, b = blockIdx.y;
  const unsigned short* Ab = M2 + (size_t)b * 65536;
  const unsigned short* Bb = xnT + ((size_t)b * 4096 + nt * 64) * 256;
  float* Cb = out + (size_t)b * 1048576 + (size_t)nt * 64;
  __shared__ unsigned short LB[2][64][32];
  const int t = threadIdx.x;
  const int wave = t >> 6, lane = t & 63, g = lane >> 4, r = lane & 15;
  const int srow = t >> 2, sslot = t & 3;
  const int ws0 = 8 * (sslot ^ (srow & 3));
  const int rslot = 8 * (g ^ (r & 3));
  const unsigned short* bg = Bb + (size_t)srow * 256 + 8 * sslot;
  const unsigned short* ar = Ab + (size_t)(wave * 64 + r) * 256 + 8 * g;
  u16x8 pb = *(const u16x8*)bg;
  f32x4 acc[4][4] = {};
  for (int kt = 0; kt < 8; ++kt) {
    const int cur = kt & 1;
    *(u16x8*)&LB[cur][srow][ws0] = pb;
    __syncthreads();
    if (kt < 7) pb = *(const u16x8*)(bg + (kt + 1) * 32);
    bf16x8 af[4], bfr[4];
#pragma unroll
    for (int mi = 0; mi < 4; ++mi)
      af[mi] = *(const bf16x8*)(ar + (size_t)(mi * 16) * 256 + kt * 32);
#pragma unroll
    for (int ni = 0; ni < 4; ++ni)
      bfr[ni] = *(const bf16x8*)&LB[cur][ni * 16 + r][rslot];
#pragma unroll
    for (int mi = 0; mi < 4; ++mi)
#pragma unroll
      for (int ni = 0; ni < 4; ++ni)
        acc[mi][ni] = __builtin_amdgcn_mfma_f32_16x16x32_bf16(af[mi], bfr[ni], acc[mi][ni], 0, 0, 0);
  }
#pragma unroll
  for (int mi = 0; mi < 4; ++mi) {
    const int row = wave * 64 + mi * 16 + 4 * g;
#pragma unroll
    for (int ni = 0; ni < 4; ++ni)
#pragma unroll
      for (int reg = 0; reg < 4; ++reg)
        Cb[(size_t)(row + reg) * 4096 + ni * 16 + r] = acc[mi][ni][reg] + bias[row + reg];
  }
}

extern "C" void kernel_launch(void* const* d_in, const int* in_sizes, int n_in,
                              void* d_out, int out_size, void* d_ws, size_t ws_size,
                              hipStream_t stream) {
  (void)in_sizes; (void)n_in; (void)out_size; (void)ws_size;
  const float* x     = (const float*)d_in[0];
  const float* gn_w  = (const float*)d_in[1];
  const float* gn_b  = (const float*)d_in[2];
  const float* qkvw  = (const float*)d_in[3];
  const float* projw = (const float*)d_in[4];
  const float* projb = (const float*)d_in[5];

  char* ws = (char*)d_ws;
  float*          partials = (float*)(ws);                       //   8 KB
  float*          stats    = (float*)(ws + 8192);                //  512 B
  unsigned short* Wb       = (unsigned short*)(ws + 16384);      //  384 KB (768x256)
  unsigned short* Mb       = (unsigned short*)(ws + 409600);     //    2 MB (P: 16x256x256)
  float*          attg     = (float*)(ws + 2506752);             //  512 KB (16x8x32x32)
  float*          rsums    = (float*)(ws + 3031040);             //   16 KB (16x8x32)
  unsigned short* WqT      = (unsigned short*)(ws + 3047424);    //  128 KB (256x256)
  unsigned short* M2       = (unsigned short*)(ws + 3178496);    //    2 MB (16x256x256)
  unsigned short* xnT      = (unsigned short*)(ws + 8388608);    //   32 MB (16x4096x256)

  k_gn_partial<<<1024, 256, 0, stream>>>(x, partials);
  k_finalize<<<209, 256, 0, stream>>>(partials, stats, qkvw, Wb, WqT);
  k_norm_t<<<4096, 256, 0, stream>>>(x, stats, gn_w, gn_b, xnT);
  (void)hipMemsetAsync(attg, 0, 540672, stream);   // attg + rsums (contiguous)
  k_attfused<<<dim3(64, 8), 256, 0, stream>>>(Wb, xnT, attg, rsums);
  k_makeM<<<128, 256, 0, stream>>>(attg, rsums, projw, Mb);
  // M2[b][256][256] = P . WqT^T  (= P.Wq)
  k_gemm_bt<true, false><<<dim3(2, 2, 16), 256, 0, stream>>>(
      Mb, WqT, (void*)M2, nullptr, 65536L, 0L, 65536L, 256);
  // out[b][256][4096] = M2 . xnT^T + bias
  k_gemm_final<<<dim3(64, 16), 256, 0, stream>>>(M2, xnT, (float*)d_out, projb);
}